// Round 2
// baseline (38644.653 us; speedup 1.0000x reference)
//
#include <hip/hip_runtime.h>

typedef _Float16 half_t;
typedef _Float16 half8 __attribute__((ext_vector_type(8)));
typedef _Float16 half4 __attribute__((ext_vector_type(4)));
typedef float float4v __attribute__((ext_vector_type(4)));

#define BB    256
#define SS    512
#define IND   64
#define HH    1024
#define HEADD 128
#define OUTD  64
#define NKT   34                      // K tiles of 32: 32 (h) + 2 (x)
#define WLDS_HALVES (4 * NKT * 512)   // 69632 halves = 139264 B
#define PRE_STRIDE 68
#define SMEM_BYTES (WLDS_HALVES * 2 + 64 * PRE_STRIDE * 4)  // 156672 B

#define MFMA16(a, b, acc) __builtin_amdgcn_mfma_f32_16x16x32_f16(a, b, acc, 0, 0, 0)

// ---------- prologue packs ----------

// x[B][S][IN] fp32 -> xA[t][mt][kt][lane][8] fp16 (A-fragment order per step)
__global__ __launch_bounds__(256) void pack_x(const float* __restrict__ x,
                                              half_t* __restrict__ xA) {
  const int t = blockIdx.x, mt = blockIdx.y;
  const int tid = threadIdx.x;
  const int kt = tid >> 7;            // 0..1
  const int lane = (tid >> 1) & 63;
  const int jh = (tid & 1) * 4;
  const int row = mt * 16 + (lane & 15);
  const int k = kt * 32 + (lane >> 4) * 8 + jh;
  const float* s = x + (size_t)row * SS * IND + (size_t)t * IND + k;
  half_t* d = xA + (((size_t)t * 16 + mt) * 2 + kt) * 512 + lane * 8 + jh;
  d[0] = (half_t)s[0]; d[1] = (half_t)s[1];
  d[2] = (half_t)s[2]; d[3] = (half_t)s[3];
}

// row-major fp32 [N][K] -> fp16 B-fragment order [cb][kt][lane][8]
__global__ __launch_bounds__(256) void frag_pack(const float* __restrict__ src,
                                                 half_t* __restrict__ dst, int K) {
  const int cb = blockIdx.x;
  const int tid = threadIdx.x;
  const int lane = tid & 63;
  const int u = tid >> 6;
  const int nkt = K >> 5;
  const int row = cb * 16 + (lane & 15);
  for (int kt = u; kt < nkt; kt += 4) {
    const int k = kt * 32 + (lane >> 4) * 8;
    const float* s = src + (size_t)row * K + k;
    half8 h;
    #pragma unroll
    for (int j = 0; j < 8; ++j) h[j] = (half_t)s[j];
    *(half8*)(dst + ((size_t)cb * nkt + kt) * 512 + lane * 8) = h;
  }
}

// ---------- persistent LSTM kernel (cooperative, 256 WGs = 1/CU) ----------
__global__ __launch_bounds__(256, 1) void lstm_persistent(
    const float* __restrict__ W_hh, const float* __restrict__ W_ih,
    const float* __restrict__ b_ih, const float* __restrict__ b_hh,
    const half_t* __restrict__ xA, const half_t* __restrict__ Wd_f,
    const float* __restrict__ bd, const half_t* __restrict__ Wd2_f,
    const float* __restrict__ bd2, half_t* __restrict__ hA,
    float* __restrict__ c, half_t* __restrict__ dbuf,
    float* __restrict__ out, unsigned int* __restrict__ cnt) {
  extern __shared__ char smem[];
  half_t* Wlds = (half_t*)smem;
  float* pre = (float*)(smem + (size_t)WLDS_HALVES * 2);

  const int wg = blockIdx.x;
  const int mtile = wg >> 6;          // 0..3  (batch rows m0..m0+63)
  const int jtile = wg & 63;          // 0..63 (h cols j0..j0+15, all 4 gates)
  const int m0 = mtile * 64;
  const int j0 = jtile * 16;
  const int tid = threadIdx.x;
  const int wave = tid >> 6;
  const int lane = tid & 63;
  const int rn = lane & 15;
  const int kq = lane >> 4;

  // ---- stage W gate-slice into LDS in B-fragment order (wave g -> gate g) ----
  {
    const int g = wave;
    const int row = g * HH + j0 + rn;
    for (int kt = 0; kt < NKT; ++kt) {
      const int k = kt * 32 + kq * 8;
      const float* s = (k < HH) ? (W_hh + (size_t)row * HH + k)
                                : (W_ih + (size_t)row * IND + (k - HH));
      half8 hv;
      #pragma unroll
      for (int j = 0; j < 8; ++j) hv[j] = (half_t)s[j];
      *(half8*)(Wlds + ((size_t)g * NKT + kt) * 512 + lane * 8) = hv;
    }
  }

  // ---- preload bias sums for cell update (fixed per thread) ----
  const int cm = tid >> 2;            // 0..63 local row
  const int hl = (tid & 3) * 4;       // 0,4,8,12 local col base
  float bsum[4][4];
  #pragma unroll
  for (int g = 0; g < 4; ++g) {
    const float4v bi = *(const float4v*)(b_ih + g * HH + j0 + hl);
    const float4v bh = *(const float4v*)(b_hh + g * HH + j0 + hl);
    #pragma unroll
    for (int j = 0; j < 4; ++j) bsum[g][j] = bi[j] + bh[j];
  }

  const int rh = wave >> 1, ch = wave & 1;   // 2x2 wave grid over 64x64 tile
  const int mtA = mtile * 4 + rh * 2;
  const int cb0 = ch * 2;

  __syncthreads();

  for (int t = 0; t <= SS + 1; ++t) {
    // ---- acquire: h_{t-1} (and dbuf) complete for this mtile ----
    if (t > 0) {
      if (tid == 0) {
        const unsigned target = (unsigned)(64 * t);
        while (__hip_atomic_load(cnt + mtile, __ATOMIC_ACQUIRE,
                                 __HIP_MEMORY_SCOPE_AGENT) < target)
          __builtin_amdgcn_s_sleep(2);
      }
      __syncthreads();
      __threadfence();
    }
    const int pbuf = t & 1;           // buffer holding h_{t-1}
    const int nbuf = pbuf ^ 1;

    if (t < SS) {
      // ---- gates GEMM: 64 rows x 64 gate-cols, K=1088 ----
      float4v a00 = {0.f, 0.f, 0.f, 0.f}, a01 = {0.f, 0.f, 0.f, 0.f};
      float4v a10 = {0.f, 0.f, 0.f, 0.f}, a11 = {0.f, 0.f, 0.f, 0.f};
      const half_t* ap0 = hA + ((size_t)(pbuf * 16 + mtA) * 32) * 512 + lane * 8;
      const half_t* ap1 = ap0 + 32 * 512;
      const half_t* bp0 = Wlds + (size_t)cb0 * NKT * 512 + lane * 8;
      const half_t* bp1 = bp0 + NKT * 512;
      #pragma unroll 4
      for (int kt = 0; kt < 32; ++kt) {
        const half8 av0 = *(const half8*)(ap0); ap0 += 512;
        const half8 av1 = *(const half8*)(ap1); ap1 += 512;
        const half8 bv0 = *(const half8*)(bp0); bp0 += 512;
        const half8 bv1 = *(const half8*)(bp1); bp1 += 512;
        a00 = MFMA16(av0, bv0, a00); a01 = MFMA16(av0, bv1, a01);
        a10 = MFMA16(av1, bv0, a10); a11 = MFMA16(av1, bv1, a11);
      }
      const half_t* xp = xA + ((size_t)t * 16 + mtA) * 1024 + lane * 8;
      #pragma unroll
      for (int kt = 0; kt < 2; ++kt) {
        const half8 av0 = *(const half8*)(xp);
        const half8 av1 = *(const half8*)(xp + 1024);
        const half8 bv0 = *(const half8*)(bp0); bp0 += 512;
        const half8 bv1 = *(const half8*)(bp1); bp1 += 512;
        xp += 512;
        a00 = MFMA16(av0, bv0, a00); a01 = MFMA16(av0, bv1, a01);
        a10 = MFMA16(av1, bv0, a10); a11 = MFMA16(av1, bv1, a11);
      }

      // ---- write pre-activations to LDS ----
      #pragma unroll
      for (int r = 0; r < 4; ++r) {
        const int rl = rh * 32 + kq * 4 + r;
        const int cl = ch * 32 + rn;
        pre[rl * PRE_STRIDE + cl] = a00[r];
        pre[rl * PRE_STRIDE + cl + 16] = a01[r];
        pre[(rl + 16) * PRE_STRIDE + cl] = a10[r];
        pre[(rl + 16) * PRE_STRIDE + cl + 16] = a11[r];
      }
      __syncthreads();

      // ---- cell update ----
      float4v pg[4];
      #pragma unroll
      for (int g = 0; g < 4; ++g)
        pg[g] = *(const float4v*)(pre + cm * PRE_STRIDE + g * 16 + hl);
      float4v cold = *(const float4v*)(c + (size_t)(m0 + cm) * HH + j0 + hl);
      float4v cnew;
      half4 hnew;
      #pragma unroll
      for (int jj = 0; jj < 4; ++jj) {
        const float ig = pg[0][jj] + bsum[0][jj];
        const float fg = pg[1][jj] + bsum[1][jj];
        const float gg = pg[2][jj] + bsum[2][jj];
        const float og = pg[3][jj] + bsum[3][jj];
        const float is = 1.f / (1.f + __expf(-ig));
        const float fs = 1.f / (1.f + __expf(-fg));
        const float os = 1.f / (1.f + __expf(-og));
        const float gt = tanhf(gg);
        const float cn = fs * cold[jj] + is * gt;
        cnew[jj] = cn;
        hnew[jj] = (half_t)(os * tanhf(cn));
      }
      *(float4v*)(c + (size_t)(m0 + cm) * HH + j0 + hl) = cnew;
      {
        const int col = j0 + hl;
        const int mtw = (m0 + cm) >> 4;
        const int ktw = col >> 5;
        const int lw = ((col & 31) >> 3) * 16 + (cm & 15);
        const int jw = col & 7;
        *(half4*)(hA + (((size_t)(nbuf * 16 + mtw) * 32 + ktw) * 64 + lw) * 8 + jw) = hnew;
      }
    }

    // ---- dense1 for h_{t-1}: 32 one-wave tasks per mtile ----
    if (t >= 1 && t <= SS && jtile < 32 && wave == 0) {
      const int rb = jtile >> 3, cb = jtile & 7;
      const int mt = mtile * 4 + rb;
      const half_t* ap = hA + ((size_t)(pbuf * 16 + mt) * 32) * 512 + lane * 8;
      const half_t* bp = Wd_f + (size_t)cb * 32 * 512 + lane * 8;
      float4v acc = {0.f, 0.f, 0.f, 0.f};
      #pragma unroll 4
      for (int kt = 0; kt < 32; ++kt) {
        acc = MFMA16(*(const half8*)ap, *(const half8*)bp, acc);
        ap += 512; bp += 512;
      }
      const int dcol = cb * 16 + rn;
      const float bv = bd[dcol];
      const int ktd = dcol >> 5;
      const int lwb = ((dcol & 31) >> 3) * 16;
      const int jd = dcol & 7;
      half_t* db = dbuf + (((size_t)((t - 1) & 1) * 16 + mt) * 4 + ktd) * 512 + jd;
      #pragma unroll
      for (int r = 0; r < 4; ++r) {
        const int rowl = kq * 4 + r;
        db[(size_t)(lwb + rowl) * 8] = (half_t)fmaxf(acc[r] + bv, 0.f);
      }
    }

    // ---- dense2 for out step t-2: 16 one-wave tasks per mtile ----
    if (t >= 2 && jtile >= 32 && jtile < 48 && wave == 0) {
      const int task = jtile - 32;
      const int rb = task >> 2, cb2 = task & 3;
      const int mt = mtile * 4 + rb;
      const half_t* ap = dbuf + (((size_t)((t - 2) & 1) * 16 + mt) * 4) * 512 + lane * 8;
      const half_t* bp = Wd2_f + (size_t)cb2 * 4 * 512 + lane * 8;
      float4v acc = {0.f, 0.f, 0.f, 0.f};
      #pragma unroll
      for (int kt = 0; kt < 4; ++kt) {
        acc = MFMA16(*(const half8*)(ap + kt * 512), *(const half8*)(bp + kt * 512), acc);
      }
      const int ocol = cb2 * 16 + rn;
      const float bv = bd2[ocol];
      #pragma unroll
      for (int r = 0; r < 4; ++r) {
        const int row = m0 + rb * 16 + kq * 4 + r;
        out[(size_t)row * (SS * OUTD) + (size_t)(t - 2) * OUTD + ocol] = acc[r] + bv;
      }
    }

    // ---- release ----
    if (t <= SS) {
      __threadfence();
      __syncthreads();
      if (tid == 0)
        __hip_atomic_fetch_add(cnt + mtile, 1u, __ATOMIC_RELEASE,
                               __HIP_MEMORY_SCOPE_AGENT);
    }
  }
}

extern "C" void kernel_launch(void* const* d_in, const int* in_sizes, int n_in,
                              void* d_out, int out_size, void* d_ws, size_t ws_size,
                              hipStream_t stream) {
  const float* x        = (const float*)d_in[0];
  const float* W_ih     = (const float*)d_in[1];
  const float* b_ih     = (const float*)d_in[2];
  const float* W_hh     = (const float*)d_in[3];
  const float* b_hh     = (const float*)d_in[4];
  const float* W_dense  = (const float*)d_in[5];
  const float* b_dense  = (const float*)d_in[6];
  const float* W_dense2 = (const float*)d_in[7];
  const float* b_dense2 = (const float*)d_in[8];
  float* out = (float*)d_out;

  char* p = (char*)d_ws;
  half_t* xA    = (half_t*)p; p += (size_t)SS * 16 * 1024 * 2;    // 16.8 MB
  half_t* Wd_f  = (half_t*)p; p += (size_t)8 * 32 * 512 * 2;      // 256 KB
  half_t* Wd2_f = (half_t*)p; p += (size_t)4 * 4 * 512 * 2;       // 16 KB
  half_t* hA    = (half_t*)p; p += (size_t)2 * 16 * 32 * 512 * 2; // 1 MB
  half_t* dbuf  = (half_t*)p; p += (size_t)2 * 16 * 4 * 512 * 2;  // 128 KB
  float*  c     = (float*)p;  p += (size_t)BB * HH * 4;           // 1 MB
  unsigned int* cnt = (unsigned int*)p; p += 128;

  hipMemsetAsync(hA, 0, (size_t)2 * 16 * 32 * 512 * 2, stream);
  hipMemsetAsync(c, 0, (size_t)BB * HH * 4, stream);
  hipMemsetAsync(cnt, 0, 128, stream);

  pack_x<<<dim3(SS, 16), 256, 0, stream>>>(x, xA);
  frag_pack<<<HEADD / 16, 256, 0, stream>>>(W_dense, Wd_f, HH);
  frag_pack<<<OUTD / 16, 256, 0, stream>>>(W_dense2, Wd2_f, HEADD);

  hipFuncSetAttribute((const void*)lstm_persistent,
                      hipFuncAttributeMaxDynamicSharedMemorySize, SMEM_BYTES);
  void* args[] = {(void*)&W_hh, (void*)&W_ih, (void*)&b_ih, (void*)&b_hh,
                  (void*)&xA, (void*)&Wd_f, (void*)&b_dense,
                  (void*)&Wd2_f, (void*)&b_dense2, (void*)&hA, (void*)&c,
                  (void*)&dbuf, (void*)&out, (void*)&cnt};
  hipLaunchCooperativeKernel((void*)lstm_persistent, dim3(256), dim3(256),
                             args, SMEM_BYTES, stream);
}

// Round 3
// 8093.421 us; speedup vs baseline: 4.7748x; 4.7748x over previous
//
#include <hip/hip_runtime.h>

typedef _Float16 half_t;
typedef _Float16 half8 __attribute__((ext_vector_type(8)));
typedef _Float16 half4 __attribute__((ext_vector_type(4)));
typedef float float4v __attribute__((ext_vector_type(4)));

#define BB    256
#define SS    512
#define IND   64
#define HH    1024
#define HEADD 128
#define OUTD  64
#define NKT   34                      // K tiles of 32: 32 (h) + 2 (x)
#define WLDS_HALVES (4 * NKT * 512)   // 69632 halves = 139264 B
#define PRE_STRIDE 68
#define SMEM_BYTES (WLDS_HALVES * 2 + 64 * PRE_STRIDE * 4)  // 156672 B

#define MFMA16(a, b, acc) __builtin_amdgcn_mfma_f32_16x16x32_f16(a, b, acc, 0, 0, 0)

// LLC-coherent (agent-scope, cache-bypassing) accessors. Relaxed atomics at
// AGENT scope compile to sc-flagged global ops served at the Infinity Cache —
// no buffer_inv / buffer_wbl2 anywhere in the hot loop.
__device__ __forceinline__ half8 aload16(const half_t* p) {
  union { unsigned long long u[2]; half8 h; } r;
  const unsigned long long* q = (const unsigned long long*)p;
  r.u[0] = __hip_atomic_load(q, __ATOMIC_RELAXED, __HIP_MEMORY_SCOPE_AGENT);
  r.u[1] = __hip_atomic_load(q + 1, __ATOMIC_RELAXED, __HIP_MEMORY_SCOPE_AGENT);
  return r.h;
}
__device__ __forceinline__ void astore8(half_t* p, half4 v) {
  union { half4 h; unsigned long long u; } r; r.h = v;
  __hip_atomic_store((unsigned long long*)p, r.u, __ATOMIC_RELAXED,
                     __HIP_MEMORY_SCOPE_AGENT);
}
__device__ __forceinline__ void astore2(half_t* p, half_t v) {
  union { half_t h; unsigned short u; } r; r.h = v;
  __hip_atomic_store((unsigned short*)p, r.u, __ATOMIC_RELAXED,
                     __HIP_MEMORY_SCOPE_AGENT);
}

// ---------- prologue packs ----------

// x[B][S][IN] fp32 -> xA[t][mt][kt][lane][8] fp16 (A-fragment order per step)
__global__ __launch_bounds__(256) void pack_x(const float* __restrict__ x,
                                              half_t* __restrict__ xA) {
  const int t = blockIdx.x, mt = blockIdx.y;
  const int tid = threadIdx.x;
  const int kt = tid >> 7;            // 0..1
  const int lane = (tid >> 1) & 63;
  const int jh = (tid & 1) * 4;
  const int row = mt * 16 + (lane & 15);
  const int k = kt * 32 + (lane >> 4) * 8 + jh;
  const float* s = x + (size_t)row * SS * IND + (size_t)t * IND + k;
  half_t* d = xA + (((size_t)t * 16 + mt) * 2 + kt) * 512 + lane * 8 + jh;
  d[0] = (half_t)s[0]; d[1] = (half_t)s[1];
  d[2] = (half_t)s[2]; d[3] = (half_t)s[3];
}

// row-major fp32 [N][K] -> fp16 B-fragment order [cb][kt][lane][8]
__global__ __launch_bounds__(256) void frag_pack(const float* __restrict__ src,
                                                 half_t* __restrict__ dst, int K) {
  const int cb = blockIdx.x;
  const int tid = threadIdx.x;
  const int lane = tid & 63;
  const int u = tid >> 6;
  const int nkt = K >> 5;
  const int row = cb * 16 + (lane & 15);
  for (int kt = u; kt < nkt; kt += 4) {
    const int k = kt * 32 + (lane >> 4) * 8;
    const float* s = src + (size_t)row * K + k;
    half8 h;
    #pragma unroll
    for (int j = 0; j < 8; ++j) h[j] = (half_t)s[j];
    *(half8*)(dst + ((size_t)cb * nkt + kt) * 512 + lane * 8) = h;
  }
}

// ---------- persistent LSTM kernel (cooperative, 256 WGs = 1/CU) ----------
__global__ __launch_bounds__(256, 1) void lstm_persistent(
    const float* __restrict__ W_hh, const float* __restrict__ W_ih,
    const float* __restrict__ b_ih, const float* __restrict__ b_hh,
    const half_t* __restrict__ xA, const half_t* __restrict__ Wd_f,
    const float* __restrict__ bd, const half_t* __restrict__ Wd2_f,
    const float* __restrict__ bd2, half_t* __restrict__ hA,
    half_t* __restrict__ dbuf, float* __restrict__ out,
    unsigned int* __restrict__ slots) {
  extern __shared__ char smem[];
  half_t* Wlds = (half_t*)smem;
  float* pre = (float*)(smem + (size_t)WLDS_HALVES * 2);

  const int wg = blockIdx.x;
  const int mtile = wg >> 6;          // 0..3  (batch rows m0..m0+63)
  const int jtile = wg & 63;          // 0..63 (h cols j0..j0+15, all 4 gates)
  const int m0 = mtile * 64;
  const int j0 = jtile * 16;
  const int tid = threadIdx.x;
  const int wave = tid >> 6;
  const int lane = tid & 63;
  const int rn = lane & 15;
  const int kq = lane >> 4;

  // ---- stage W gate-slice into LDS in B-fragment order (wave g -> gate g) ----
  {
    const int g = wave;
    const int row = g * HH + j0 + rn;
    for (int kt = 0; kt < NKT; ++kt) {
      const int k = kt * 32 + kq * 8;
      const float* s = (k < HH) ? (W_hh + (size_t)row * HH + k)
                                : (W_ih + (size_t)row * IND + (k - HH));
      half8 hv;
      #pragma unroll
      for (int j = 0; j < 8; ++j) hv[j] = (half_t)s[j];
      *(half8*)(Wlds + ((size_t)g * NKT + kt) * 512 + lane * 8) = hv;
    }
  }

  // ---- per-thread persistent state for cell update ----
  const int cm = tid >> 2;            // 0..63 local row
  const int hl = (tid & 3) * 4;       // 0,4,8,12 local col base
  float bsum[4][4];
  #pragma unroll
  for (int g = 0; g < 4; ++g) {
    const float4v bi = *(const float4v*)(b_ih + g * HH + j0 + hl);
    const float4v bh = *(const float4v*)(b_hh + g * HH + j0 + hl);
    #pragma unroll
    for (int j = 0; j < 4; ++j) bsum[g][j] = bi[j] + bh[j];
  }
  float4v creg = {0.f, 0.f, 0.f, 0.f};  // c[m0+cm][j0+hl..+3], lives in VGPRs

  const int rh = wave >> 1, ch = wave & 1;   // 2x2 wave grid over 64x64 tile
  const int mtA = mtile * 4 + rh * 2;
  const int cb0 = ch * 2;

  __syncthreads();

  for (int t = 0; t <= SS + 1; ++t) {
    // ---- acquire: all 64 WGs of this mtile finished step t-1 ----
    if (t > 0) {
      if (wave == 0) {
        const unsigned target = (unsigned)t;
        const unsigned int* sl = slots + mtile * 64 + lane;
        while (__hip_atomic_load(sl, __ATOMIC_RELAXED,
                                 __HIP_MEMORY_SCOPE_AGENT) < target)
          __builtin_amdgcn_s_sleep(2);
      }
      __syncthreads();
    }
    const int pbuf = t & 1;           // buffer holding h_{t-1}
    const int nbuf = pbuf ^ 1;

    if (t < SS) {
      // ---- gates GEMM: 64 rows x 64 gate-cols, K=1088 ----
      float4v a00 = {0.f, 0.f, 0.f, 0.f}, a01 = {0.f, 0.f, 0.f, 0.f};
      float4v a10 = {0.f, 0.f, 0.f, 0.f}, a11 = {0.f, 0.f, 0.f, 0.f};
      const half_t* ap0 = hA + ((size_t)(pbuf * 16 + mtA) * 32) * 512 + lane * 8;
      const half_t* ap1 = ap0 + 32 * 512;
      const half_t* bp0 = Wlds + (size_t)cb0 * NKT * 512 + lane * 8;
      const half_t* bp1 = bp0 + NKT * 512;
      #pragma unroll 4
      for (int kt = 0; kt < 32; ++kt) {
        const half8 av0 = aload16(ap0); ap0 += 512;
        const half8 av1 = aload16(ap1); ap1 += 512;
        const half8 bv0 = *(const half8*)(bp0); bp0 += 512;
        const half8 bv1 = *(const half8*)(bp1); bp1 += 512;
        a00 = MFMA16(av0, bv0, a00); a01 = MFMA16(av0, bv1, a01);
        a10 = MFMA16(av1, bv0, a10); a11 = MFMA16(av1, bv1, a11);
      }
      const half_t* xp = xA + ((size_t)t * 16 + mtA) * 1024 + lane * 8;
      #pragma unroll
      for (int kt = 0; kt < 2; ++kt) {
        const half8 av0 = *(const half8*)(xp);
        const half8 av1 = *(const half8*)(xp + 1024);
        const half8 bv0 = *(const half8*)(bp0); bp0 += 512;
        const half8 bv1 = *(const half8*)(bp1); bp1 += 512;
        xp += 512;
        a00 = MFMA16(av0, bv0, a00); a01 = MFMA16(av0, bv1, a01);
        a10 = MFMA16(av1, bv0, a10); a11 = MFMA16(av1, bv1, a11);
      }

      // ---- write pre-activations to LDS ----
      #pragma unroll
      for (int r = 0; r < 4; ++r) {
        const int rl = rh * 32 + kq * 4 + r;
        const int cl = ch * 32 + rn;
        pre[rl * PRE_STRIDE + cl] = a00[r];
        pre[rl * PRE_STRIDE + cl + 16] = a01[r];
        pre[(rl + 16) * PRE_STRIDE + cl] = a10[r];
        pre[(rl + 16) * PRE_STRIDE + cl + 16] = a11[r];
      }
      __syncthreads();

      // ---- cell update (c in registers) ----
      float4v pg[4];
      #pragma unroll
      for (int g = 0; g < 4; ++g)
        pg[g] = *(const float4v*)(pre + cm * PRE_STRIDE + g * 16 + hl);
      half4 hnew;
      #pragma unroll
      for (int jj = 0; jj < 4; ++jj) {
        const float ig = pg[0][jj] + bsum[0][jj];
        const float fg = pg[1][jj] + bsum[1][jj];
        const float gg = pg[2][jj] + bsum[2][jj];
        const float og = pg[3][jj] + bsum[3][jj];
        const float is = 1.f / (1.f + __expf(-ig));
        const float fs = 1.f / (1.f + __expf(-fg));
        const float os = 1.f / (1.f + __expf(-og));
        const float gt = tanhf(gg);
        const float cn = fs * creg[jj] + is * gt;
        creg[jj] = cn;
        hnew[jj] = (half_t)(os * tanhf(cn));
      }
      {
        const int col = j0 + hl;
        const int mtw = (m0 + cm) >> 4;
        const int ktw = col >> 5;
        const int lw = ((col & 31) >> 3) * 16 + (cm & 15);
        const int jw = col & 7;
        astore8(hA + (((size_t)(nbuf * 16 + mtw) * 32 + ktw) * 64 + lw) * 8 + jw, hnew);
      }
    }

    // ---- dense1 for h_{t-1}: 32 one-wave tasks per mtile ----
    if (t >= 1 && t <= SS && jtile < 32 && wave == 0) {
      const int rb = jtile >> 3, cb = jtile & 7;
      const int mt = mtile * 4 + rb;
      const half_t* ap = hA + ((size_t)(pbuf * 16 + mt) * 32) * 512 + lane * 8;
      const half_t* bp = Wd_f + (size_t)cb * 32 * 512 + lane * 8;
      float4v acc = {0.f, 0.f, 0.f, 0.f};
      #pragma unroll 4
      for (int kt = 0; kt < 32; ++kt) {
        acc = MFMA16(aload16(ap), *(const half8*)bp, acc);
        ap += 512; bp += 512;
      }
      const int dcol = cb * 16 + rn;
      const float bv = bd[dcol];
      // dbuf row-major: [buf][mt 0..15][row 0..15][128]
      half_t* db = dbuf + (((size_t)((t - 1) & 1) * 16 + mt) * 16) * HEADD + dcol;
      #pragma unroll
      for (int r = 0; r < 4; ++r) {
        const int rowl = kq * 4 + r;
        astore2(db + (size_t)rowl * HEADD, (half_t)fmaxf(acc[r] + bv, 0.f));
      }
    }

    // ---- dense2 for out step t-2: 16 one-wave tasks per mtile ----
    if (t >= 2 && jtile >= 32 && jtile < 48 && wave == 0) {
      const int task = jtile - 32;
      const int rb = task >> 2, cb2 = task & 3;
      const int mt = mtile * 4 + rb;
      const half_t* ap =
          dbuf + (((size_t)((t - 2) & 1) * 16 + mt) * 16) * HEADD;
      const half_t* bp = Wd2_f + (size_t)cb2 * 4 * 512 + lane * 8;
      float4v acc = {0.f, 0.f, 0.f, 0.f};
      #pragma unroll
      for (int kt = 0; kt < 4; ++kt) {
        const half8 af = aload16(ap + (size_t)rn * HEADD + kt * 32 + kq * 8);
        acc = MFMA16(af, *(const half8*)(bp + kt * 512), acc);
      }
      const int ocol = cb2 * 16 + rn;
      const float bv = bd2[ocol];
      #pragma unroll
      for (int r = 0; r < 4; ++r) {
        const int row = m0 + rb * 16 + kq * 4 + r;
        out[(size_t)row * (SS * OUTD) + (size_t)(t - 2) * OUTD + ocol] = acc[r] + bv;
      }
    }

    // ---- release: stores acked at LLC, then publish slot ----
    if (t <= SS) {
      __builtin_amdgcn_s_waitcnt(0);  // this wave's agent stores are at LLC
      __syncthreads();                // all waves drained (compiler adds waitcnt)
      if (tid == 0)
        __hip_atomic_store(slots + mtile * 64 + jtile, (unsigned)(t + 1),
                           __ATOMIC_RELAXED, __HIP_MEMORY_SCOPE_AGENT);
    }
  }
}

extern "C" void kernel_launch(void* const* d_in, const int* in_sizes, int n_in,
                              void* d_out, int out_size, void* d_ws, size_t ws_size,
                              hipStream_t stream) {
  const float* x        = (const float*)d_in[0];
  const float* W_ih     = (const float*)d_in[1];
  const float* b_ih     = (const float*)d_in[2];
  const float* W_hh     = (const float*)d_in[3];
  const float* b_hh     = (const float*)d_in[4];
  const float* W_dense  = (const float*)d_in[5];
  const float* b_dense  = (const float*)d_in[6];
  const float* W_dense2 = (const float*)d_in[7];
  const float* b_dense2 = (const float*)d_in[8];
  float* out = (float*)d_out;

  char* p = (char*)d_ws;
  half_t* xA    = (half_t*)p; p += (size_t)SS * 16 * 1024 * 2;    // 16.8 MB
  half_t* Wd_f  = (half_t*)p; p += (size_t)8 * 32 * 512 * 2;      // 256 KB
  half_t* Wd2_f = (half_t*)p; p += (size_t)4 * 4 * 512 * 2;       // 16 KB
  half_t* hA    = (half_t*)p; p += (size_t)2 * 16 * 32 * 512 * 2; // 1 MB
  half_t* dbuf  = (half_t*)p; p += (size_t)2 * 16 * 16 * 128 * 2; // 128 KB
  unsigned int* slots = (unsigned int*)p; p += 4 * 64 * 4;

  hipMemsetAsync(hA, 0, (size_t)2 * 16 * 32 * 512 * 2, stream);
  hipMemsetAsync(slots, 0, 4 * 64 * 4, stream);

  pack_x<<<dim3(SS, 16), 256, 0, stream>>>(x, xA);
  frag_pack<<<HEADD / 16, 256, 0, stream>>>(W_dense, Wd_f, HH);
  frag_pack<<<OUTD / 16, 256, 0, stream>>>(W_dense2, Wd2_f, HEADD);

  hipFuncSetAttribute((const void*)lstm_persistent,
                      hipFuncAttributeMaxDynamicSharedMemorySize, SMEM_BYTES);
  void* args[] = {(void*)&W_hh, (void*)&W_ih, (void*)&b_ih, (void*)&b_hh,
                  (void*)&xA, (void*)&Wd_f, (void*)&b_dense,
                  (void*)&Wd2_f, (void*)&b_dense2, (void*)&hA,
                  (void*)&dbuf, (void*)&out, (void*)&slots};
  hipLaunchCooperativeKernel((void*)lstm_persistent, dim3(256), dim3(256),
                             args, SMEM_BYTES, stream);
}

// Round 4
// 7847.929 us; speedup vs baseline: 4.9242x; 1.0313x over previous
//
#include <hip/hip_runtime.h>

typedef _Float16 half_t;
typedef _Float16 half8 __attribute__((ext_vector_type(8)));
typedef _Float16 half4 __attribute__((ext_vector_type(4)));
typedef float float4v __attribute__((ext_vector_type(4)));

#define BB    256
#define SS    512
#define IND   64
#define HH    1024
#define HEADD 128
#define OUTD  64
#define NKT   34                      // K tiles of 32: 32 (h) + 2 (x)
#define WLDS_HALVES (4 * NKT * 512)   // 69632 halves = 139264 B
#define PRE_STRIDE 68                 // padded float stride (row*68: 2-way max)
#define SMEM_BYTES (WLDS_HALVES * 2 + 4 * 16 * PRE_STRIDE * 4)  // 156672 B
#define BUFV (BB * HH)                // halves per h step-buffer (512 KB)

#define MFMA16(a, b, acc) __builtin_amdgcn_mfma_f32_16x16x32_f16(a, b, acc, 0, 0, 0)

// Rotating write-once state in device globals (not d_ws): every address is
// written exactly once per dispatch before it is read -> plain cached loads
// are coherence-safe; dispatch-boundary invalidation covers graph replays.
__device__ half_t g_hA[(size_t)(SS + 1) * BUFV];          // ~269 MB
__device__ half_t g_dbuf[(size_t)SS * 256 * HEADD];       // ~33.5 MB
__device__ unsigned int g_gslot[256];
__device__ unsigned int g_dslot[128];

__device__ __forceinline__ void astore8(half_t* p, half4 v) {
  union { half4 h; unsigned long long u; } r; r.h = v;
  __hip_atomic_store((unsigned long long*)p, r.u, __ATOMIC_RELAXED,
                     __HIP_MEMORY_SCOPE_AGENT);
}
__device__ __forceinline__ void astore2(half_t* p, half_t v) {
  union { half_t h; unsigned short u; } r; r.h = v;
  __hip_atomic_store((unsigned short*)p, r.u, __ATOMIC_RELAXED,
                     __HIP_MEMORY_SCOPE_AGENT);
}

// ---------- prologue ----------

__global__ __launch_bounds__(256) void init_state() {
  const size_t i = (size_t)blockIdx.x * 256 + threadIdx.x;  // 65536 threads
  *(unsigned long long*)(g_hA + i * 4) = 0ULL;              // zero buffer 0
  if (blockIdx.x == 0) {
    g_gslot[threadIdx.x] = 0;
    if (threadIdx.x < 128) g_dslot[threadIdx.x] = 0;
  }
}

// x[B][S][IN] fp32 -> xA[t][mt][kt][lane][8] fp16 (A-fragment order per step)
__global__ __launch_bounds__(256) void pack_x(const float* __restrict__ x,
                                              half_t* __restrict__ xA) {
  const int t = blockIdx.x, mt = blockIdx.y;
  const int tid = threadIdx.x;
  const int kt = tid >> 7;
  const int lane = (tid >> 1) & 63;
  const int jh = (tid & 1) * 4;
  const int row = mt * 16 + (lane & 15);
  const int k = kt * 32 + (lane >> 4) * 8 + jh;
  const float* s = x + (size_t)row * SS * IND + (size_t)t * IND + k;
  half_t* d = xA + (((size_t)t * 16 + mt) * 2 + kt) * 512 + lane * 8 + jh;
  d[0] = (half_t)s[0]; d[1] = (half_t)s[1];
  d[2] = (half_t)s[2]; d[3] = (half_t)s[3];
}

// row-major fp32 [N][K] -> fp16 B-fragment order [cb][kt][lane][8]
__global__ __launch_bounds__(256) void frag_pack(const float* __restrict__ src,
                                                 half_t* __restrict__ dst, int K) {
  const int cb = blockIdx.x;
  const int tid = threadIdx.x;
  const int lane = tid & 63;
  const int u = tid >> 6;
  const int nkt = K >> 5;
  const int row = cb * 16 + (lane & 15);
  for (int kt = u; kt < nkt; kt += 4) {
    const int k = kt * 32 + (lane >> 4) * 8;
    const float* s = src + (size_t)row * K + k;
    half8 h;
    #pragma unroll
    for (int j = 0; j < 8; ++j) h[j] = (half_t)s[j];
    *(half8*)(dst + ((size_t)cb * nkt + kt) * 512 + lane * 8) = h;
  }
}

// ---------- persistent LSTM kernel (cooperative, 256 WGs = 1/CU) ----------
__global__ __launch_bounds__(256, 1) void lstm_persistent(
    const float* __restrict__ W_hh, const float* __restrict__ W_ih,
    const float* __restrict__ b_ih, const float* __restrict__ b_hh,
    const half_t* __restrict__ xA, const half_t* __restrict__ Wd_f,
    const float* __restrict__ bd, const half_t* __restrict__ Wd2_f,
    const float* __restrict__ bd2, float* __restrict__ out) {
  extern __shared__ char smem[];
  half_t* Wlds = (half_t*)smem;
  float* pre = (float*)(smem + (size_t)WLDS_HALVES * 2);

  const int wg = blockIdx.x;
  const int mtile = wg >> 6;          // 0..3  (batch rows m0..m0+63)
  const int jtile = wg & 63;          // 0..63 (h cols j0..j0+15, all 4 gates)
  const int m0 = mtile * 64;
  const int j0 = jtile * 16;
  const int tid = threadIdx.x;
  const int wave = tid >> 6;
  const int lane = tid & 63;
  const int rn = lane & 15;
  const int kq = lane >> 4;

  // ---- stage W gate-slice into LDS in B-fragment order (wave g -> gate g) ----
  {
    const int row = wave * HH + j0 + rn;
    for (int kt = 0; kt < NKT; ++kt) {
      const int k = kt * 32 + kq * 8;
      const float* s = (k < HH) ? (W_hh + (size_t)row * HH + k)
                                : (W_ih + (size_t)row * IND + (k - HH));
      half8 hv;
      #pragma unroll
      for (int j = 0; j < 8; ++j) hv[j] = (half_t)s[j];
      *(half8*)(Wlds + ((size_t)wave * NKT + kt) * 512 + lane * 8) = hv;
    }
  }

  // ---- per-thread persistent cell state; wave owns row-block (mtile*4+wave) ----
  const int crow = lane >> 2;         // 0..15 row within wave's block
  const int hl = (lane & 3) * 4;      // col base 0,4,8,12
  const int cm = wave * 16 + crow;    // WG-local row 0..63
  float bsum[4][4];
  #pragma unroll
  for (int g = 0; g < 4; ++g) {
    const float4v bi = *(const float4v*)(b_ih + g * HH + j0 + hl);
    const float4v bh = *(const float4v*)(b_hh + g * HH + j0 + hl);
    #pragma unroll
    for (int j = 0; j < 4; ++j) bsum[g][j] = bi[j] + bh[j];
  }
  float4v creg = {0.f, 0.f, 0.f, 0.f};

  const int mtA = mtile * 4 + wave;   // wave's 16-row block (global mt 0..15)
  float* pw = pre + wave * (16 * PRE_STRIDE);

  // precomputed h-store address pieces
  const int col_s = j0 + hl;
  const int ktw = col_s >> 5;
  const int kqw = (col_s & 31) >> 3;
  const int jw = col_s & 7;
  const size_t hoff = (((size_t)((mtile * 4 + (cm >> 4)) * 32 + ktw)) * 64 +
                       kqw * 16 + (cm & 15)) * 8 + jw;

  __syncthreads();

  for (int t = 0; t <= SS + 1; ++t) {
    // ---- acquire gates: all 64 WGs of this mtile finished step t-1 ----
    if (t >= 1 && t <= SS) {
      if (wave == 0) {
        const unsigned int* sl = g_gslot + mtile * 64 + lane;
        while (__hip_atomic_load(sl, __ATOMIC_RELAXED,
                                 __HIP_MEMORY_SCOPE_AGENT) < (unsigned)t)
          __builtin_amdgcn_s_sleep(2);
      }
      __syncthreads();
    }

    if (t < SS) {
      // ---- gates GEMM: wave computes 16 rows x 64 gate-cols, K=1088 ----
      float4v a0 = {0.f, 0.f, 0.f, 0.f}, a1 = {0.f, 0.f, 0.f, 0.f};
      float4v a2 = {0.f, 0.f, 0.f, 0.f}, a3 = {0.f, 0.f, 0.f, 0.f};
      const half_t* ap = g_hA + (size_t)t * BUFV + ((size_t)mtA * 32) * 512 + lane * 8;
      const half_t* bp = Wlds + lane * 8;
      #pragma unroll 8
      for (int kt = 0; kt < 32; ++kt) {
        const half8 av = *(const half8*)(ap + (size_t)kt * 512);
        a0 = MFMA16(av, *(const half8*)(bp + (size_t)(0 * NKT + kt) * 512), a0);
        a1 = MFMA16(av, *(const half8*)(bp + (size_t)(1 * NKT + kt) * 512), a1);
        a2 = MFMA16(av, *(const half8*)(bp + (size_t)(2 * NKT + kt) * 512), a2);
        a3 = MFMA16(av, *(const half8*)(bp + (size_t)(3 * NKT + kt) * 512), a3);
      }
      const half_t* xp = xA + (((size_t)t * 16 + mtA) * 2) * 512 + lane * 8;
      #pragma unroll
      for (int kt = 0; kt < 2; ++kt) {
        const half8 av = *(const half8*)(xp + (size_t)kt * 512);
        a0 = MFMA16(av, *(const half8*)(bp + (size_t)(0 * NKT + 32 + kt) * 512), a0);
        a1 = MFMA16(av, *(const half8*)(bp + (size_t)(1 * NKT + 32 + kt) * 512), a1);
        a2 = MFMA16(av, *(const half8*)(bp + (size_t)(2 * NKT + 32 + kt) * 512), a2);
        a3 = MFMA16(av, *(const half8*)(bp + (size_t)(3 * NKT + 32 + kt) * 512), a3);
      }

      // ---- intra-wave pre-activation exchange (no barrier) ----
      #pragma unroll
      for (int r = 0; r < 4; ++r) {
        const int rl = (kq * 4 + r) * PRE_STRIDE;
        pw[rl + rn] = a0[r];
        pw[rl + 16 + rn] = a1[r];
        pw[rl + 32 + rn] = a2[r];
        pw[rl + 48 + rn] = a3[r];
      }

      // ---- cell update (c in registers) ----
      const float4v pg0 = *(const float4v*)(pw + crow * PRE_STRIDE + hl);
      const float4v pg1 = *(const float4v*)(pw + crow * PRE_STRIDE + 16 + hl);
      const float4v pg2 = *(const float4v*)(pw + crow * PRE_STRIDE + 32 + hl);
      const float4v pg3 = *(const float4v*)(pw + crow * PRE_STRIDE + 48 + hl);
      half4 hnew;
      #pragma unroll
      for (int jj = 0; jj < 4; ++jj) {
        const float ig = pg0[jj] + bsum[0][jj];
        const float fg = pg1[jj] + bsum[1][jj];
        const float gg = pg2[jj] + bsum[2][jj];
        const float og = pg3[jj] + bsum[3][jj];
        const float is = 1.f / (1.f + __expf(-ig));
        const float fs = 1.f / (1.f + __expf(-fg));
        const float os = 1.f / (1.f + __expf(-og));
        const float gt = tanhf(gg);
        const float cn = fs * creg[jj] + is * gt;
        creg[jj] = cn;
        hnew[jj] = (half_t)(os * tanhf(cn));
      }
      astore8(g_hA + (size_t)(t + 1) * BUFV + hoff, hnew);

      // ---- release gates: h at LLC, then publish ----
      __builtin_amdgcn_s_waitcnt(0);
      __syncthreads();
      if (tid == 0)
        __hip_atomic_store(g_gslot + mtile * 64 + jtile, (unsigned)(t + 1),
                           __ATOMIC_RELAXED, __HIP_MEMORY_SCOPE_AGENT);
    }

    // ---- dense1 for h_{t-1}: 32 one-wave tasks per mtile (off critical path) ----
    if (t >= 1 && t <= SS && jtile < 32 && wave == 0) {
      const int rb = jtile >> 3, cb = jtile & 7;
      const int mt = mtile * 4 + rb;
      const half_t* ap = g_hA + (size_t)t * BUFV + ((size_t)mt * 32) * 512 + lane * 8;
      const half_t* bp = Wd_f + (size_t)cb * 32 * 512 + lane * 8;
      float4v acc = {0.f, 0.f, 0.f, 0.f};
      #pragma unroll 8
      for (int kt = 0; kt < 32; ++kt) {
        acc = MFMA16(*(const half8*)(ap + (size_t)kt * 512),
                     *(const half8*)(bp + (size_t)kt * 512), acc);
      }
      const int dcol = cb * 16 + rn;
      const float bv = bd[dcol];
      half_t* db = g_dbuf + (((size_t)(t - 1) * 16 + mt) * 16) * HEADD + dcol;
      #pragma unroll
      for (int r = 0; r < 4; ++r)
        astore2(db + (size_t)(kq * 4 + r) * HEADD, (half_t)fmaxf(acc[r] + bv, 0.f));
      __builtin_amdgcn_s_waitcnt(0);
      if (lane == 0)
        __hip_atomic_store(g_dslot + mtile * 32 + jtile, (unsigned)t,
                           __ATOMIC_RELAXED, __HIP_MEMORY_SCOPE_AGENT);
    }

    // ---- dense2 for out step t-2: 16 one-wave tasks per mtile ----
    if (t >= 2 && jtile >= 32 && jtile < 48 && wave == 0) {
      const unsigned int* sl = g_dslot + mtile * 32 + (lane & 31);
      while (__hip_atomic_load(sl, __ATOMIC_RELAXED,
                               __HIP_MEMORY_SCOPE_AGENT) < (unsigned)(t - 1))
        __builtin_amdgcn_s_sleep(2);
      const int task = jtile - 32;
      const int rb = task >> 2, cb2 = task & 3;
      const int mt = mtile * 4 + rb;
      const half_t* ap = g_dbuf + (((size_t)(t - 2) * 16 + mt) * 16) * HEADD;
      const half_t* bp = Wd2_f + (size_t)cb2 * 4 * 512 + lane * 8;
      float4v acc = {0.f, 0.f, 0.f, 0.f};
      #pragma unroll
      for (int kt = 0; kt < 4; ++kt) {
        const half8 af = *(const half8*)(ap + (size_t)rn * HEADD + kt * 32 + kq * 8);
        acc = MFMA16(af, *(const half8*)(bp + (size_t)kt * 512), acc);
      }
      const int ocol = cb2 * 16 + rn;
      const float bv = bd2[ocol];
      #pragma unroll
      for (int r = 0; r < 4; ++r) {
        const int row = m0 + rb * 16 + kq * 4 + r;
        out[(size_t)row * (SS * OUTD) + (size_t)(t - 2) * OUTD + ocol] = acc[r] + bv;
      }
    }
  }
}

extern "C" void kernel_launch(void* const* d_in, const int* in_sizes, int n_in,
                              void* d_out, int out_size, void* d_ws, size_t ws_size,
                              hipStream_t stream) {
  const float* x        = (const float*)d_in[0];
  const float* W_ih     = (const float*)d_in[1];
  const float* b_ih     = (const float*)d_in[2];
  const float* W_hh     = (const float*)d_in[3];
  const float* b_hh     = (const float*)d_in[4];
  const float* W_dense  = (const float*)d_in[5];
  const float* b_dense  = (const float*)d_in[6];
  const float* W_dense2 = (const float*)d_in[7];
  const float* b_dense2 = (const float*)d_in[8];
  float* out = (float*)d_out;

  char* p = (char*)d_ws;
  half_t* xA    = (half_t*)p; p += (size_t)SS * 16 * 1024 * 2;  // 16.8 MB
  half_t* Wd_f  = (half_t*)p; p += (size_t)8 * 32 * 512 * 2;    // 256 KB
  half_t* Wd2_f = (half_t*)p; p += (size_t)4 * 4 * 512 * 2;     // 16 KB

  init_state<<<256, 256, 0, stream>>>();
  pack_x<<<dim3(SS, 16), 256, 0, stream>>>(x, xA);
  frag_pack<<<HEADD / 16, 256, 0, stream>>>(W_dense, Wd_f, HH);
  frag_pack<<<OUTD / 16, 256, 0, stream>>>(W_dense2, Wd2_f, HEADD);

  hipFuncSetAttribute((const void*)lstm_persistent,
                      hipFuncAttributeMaxDynamicSharedMemorySize, SMEM_BYTES);
  void* args[] = {(void*)&W_hh, (void*)&W_ih, (void*)&b_ih, (void*)&b_hh,
                  (void*)&xA, (void*)&Wd_f, (void*)&b_dense,
                  (void*)&Wd2_f, (void*)&b_dense2, (void*)&out};
  hipLaunchCooperativeKernel((void*)lstm_persistent, dim3(256), dim3(256),
                             args, SMEM_BYTES, stream);
}

// Round 6
// 7100.385 us; speedup vs baseline: 5.4426x; 1.1053x over previous
//
#include <hip/hip_runtime.h>

typedef _Float16 half_t;
typedef _Float16 half8 __attribute__((ext_vector_type(8)));
typedef _Float16 half4 __attribute__((ext_vector_type(4)));
typedef float float4v __attribute__((ext_vector_type(4)));

#define BB    256
#define SS    512
#define IND   64
#define HH    1024
#define HEADD 128
#define OUTD  64
#define NKT   34                      // K tiles of 32: 32 (h) + 2 (x)
#define WLDS_HALVES (4 * NKT * 512)   // 69632 halves = 139264 B
#define PRE_STRIDE 68                 // padded float stride
#define SMEM_BYTES (WLDS_HALVES * 2 + 4 * 16 * PRE_STRIDE * 4)  // 156672 B
#define BUFV (BB * HH)                // halves per h step-buffer (512 KB)

#define MFMA16(a, b, acc) __builtin_amdgcn_mfma_f32_16x16x32_f16(a, b, acc, 0, 0, 0)

// Rotating write-once state in device globals: every address is written at
// most once per dispatch before being read -> plain cached loads are
// coherence-safe (producer sc-stores land at LLC; consumer caches are
// invalidated at dispatch start and never touch these lines beforehand).
__device__ half_t g_hA[(size_t)(SS + 1) * BUFV];          // ~263 MB
__device__ half_t g_dbuf[(size_t)SS * 256 * HEADD];       // ~33.5 MB
// sync fabric, one uint "word", lines are 32 words (128 B):
//  [0      .. 1023]  slots: mtile*256 + (jt>>3)*32 + (jt&7)   (8 lines/mtile)
//  [1024   .. 3071]  go:    1024 + mtile*512 + copy*32        (16 lines/mtile)
//  [3072   .. 3199]  dcnt:  3072 + mtile*32                   (1 line/mtile)
__device__ unsigned int g_sync[4096];

__device__ __forceinline__ void astore8(half_t* p, half4 v) {
  union { half4 h; unsigned long long u; } r; r.h = v;
  __hip_atomic_store((unsigned long long*)p, r.u, __ATOMIC_RELAXED,
                     __HIP_MEMORY_SCOPE_AGENT);
}
__device__ __forceinline__ void astore2(half_t* p, half_t v) {
  union { half_t h; unsigned short u; } r; r.h = v;
  __hip_atomic_store((unsigned short*)p, r.u, __ATOMIC_RELAXED,
                     __HIP_MEMORY_SCOPE_AGENT);
}

// ---------- prologue ----------

__global__ __launch_bounds__(256) void init_state() {
  const size_t i = (size_t)blockIdx.x * 256 + threadIdx.x;  // 65536 threads
  *(unsigned long long*)(g_hA + i * 4) = 0ULL;              // zero buffer 0
  if (blockIdx.x == 0)
    for (int j = threadIdx.x; j < 4096; j += 256) g_sync[j] = 0;
}

// x[B][S][IN] fp32 -> xA[t][mt][kt][lane][8] fp16 (A-fragment order per step)
__global__ __launch_bounds__(256) void pack_x(const float* __restrict__ x,
                                              half_t* __restrict__ xA) {
  const int t = blockIdx.x, mt = blockIdx.y;
  const int tid = threadIdx.x;
  const int kt = tid >> 7;
  const int lane = (tid >> 1) & 63;
  const int jh = (tid & 1) * 4;
  const int row = mt * 16 + (lane & 15);
  const int k = kt * 32 + (lane >> 4) * 8 + jh;
  const float* s = x + (size_t)row * SS * IND + (size_t)t * IND + k;
  half_t* d = xA + (((size_t)t * 16 + mt) * 2 + kt) * 512 + lane * 8 + jh;
  d[0] = (half_t)s[0]; d[1] = (half_t)s[1];
  d[2] = (half_t)s[2]; d[3] = (half_t)s[3];
}

// row-major fp32 [N][K] -> fp16 B-fragment order [cb][kt][lane][8]
__global__ __launch_bounds__(256) void frag_pack(const float* __restrict__ src,
                                                 half_t* __restrict__ dst, int K) {
  const int cb = blockIdx.x;
  const int tid = threadIdx.x;
  const int lane = tid & 63;
  const int u = tid >> 6;
  const int nkt = K >> 5;
  const int row = cb * 16 + (lane & 15);
  for (int kt = u; kt < nkt; kt += 4) {
    const int k = kt * 32 + (lane >> 4) * 8;
    const float* s = src + (size_t)row * K + k;
    half8 h;
    #pragma unroll
    for (int j = 0; j < 8; ++j) h[j] = (half_t)s[j];
    *(half8*)(dst + ((size_t)cb * nkt + kt) * 512 + lane * 8) = h;
  }
}

// ---------- persistent LSTM kernel (cooperative, 256 WGs = 1/CU) ----------
// Geometry identical to R4 (verified correct): WG (mtile 0..3, jtile 0..63) =
// 64 rows x 16 h-cols x 4 gates; wave = one 16-row block x all 4 gates.
__global__ __launch_bounds__(256, 1) void lstm_persistent(
    const float* __restrict__ W_hh, const float* __restrict__ W_ih,
    const float* __restrict__ b_ih, const float* __restrict__ b_hh,
    const half_t* __restrict__ xA, const half_t* __restrict__ Wd_f,
    const float* __restrict__ bd, const half_t* __restrict__ Wd2_f,
    const float* __restrict__ bd2, float* __restrict__ out) {
  extern __shared__ char smem[];
  half_t* Wlds = (half_t*)smem;
  float* pre = (float*)(smem + (size_t)WLDS_HALVES * 2);

  const int wg = blockIdx.x;
  const int mtile = wg >> 6;          // 0..3  (batch rows m0..m0+63)
  const int jtile = wg & 63;          // 0..63 (h cols j0..j0+15, all 4 gates)
  const int m0 = mtile * 64;
  const int j0 = jtile * 16;
  const int tid = threadIdx.x;
  const int wave = tid >> 6;
  const int lane = tid & 63;
  const int rn = lane & 15;
  const int kq = lane >> 4;

  // ---- stage W gate-slice into LDS in B-fragment order (wave g -> gate g) ----
  {
    const int row = wave * HH + j0 + rn;
    for (int kt = 0; kt < NKT; ++kt) {
      const int k = kt * 32 + kq * 8;
      const float* s = (k < HH) ? (W_hh + (size_t)row * HH + k)
                                : (W_ih + (size_t)row * IND + (k - HH));
      half8 hv;
      #pragma unroll
      for (int j = 0; j < 8; ++j) hv[j] = (half_t)s[j];
      *(half8*)(Wlds + ((size_t)wave * NKT + kt) * 512 + lane * 8) = hv;
    }
  }

  // ---- per-thread persistent cell state; wave owns row-block (mtile*4+wave) ----
  const int crow = lane >> 2;         // 0..15 row within wave's block
  const int hl = (lane & 3) * 4;      // col base 0,4,8,12
  const int cm = wave * 16 + crow;    // WG-local row 0..63
  float bsum[4][4];
  #pragma unroll
  for (int g = 0; g < 4; ++g) {
    const float4v bi = *(const float4v*)(b_ih + g * HH + j0 + hl);
    const float4v bh = *(const float4v*)(b_hh + g * HH + j0 + hl);
    #pragma unroll
    for (int j = 0; j < 4; ++j) bsum[g][j] = bi[j] + bh[j];
  }
  float4v creg = {0.f, 0.f, 0.f, 0.f};

  const int mtA = mtile * 4 + wave;   // wave's 16-row block (global mt 0..15)
  float* pw = pre + wave * (16 * PRE_STRIDE);

  // precomputed h-store address pieces
  const int col_s = j0 + hl;
  const int ktw = col_s >> 5;
  const int kqw = (col_s & 31) >> 3;
  const int jw = col_s & 7;
  const size_t hoff = (((size_t)((mtile * 4 + (cm >> 4)) * 32 + ktw)) * 64 +
                       kqw * 16 + (cm & 15)) * 8 + jw;

  const half_t* habase = g_hA + ((size_t)mtA * 32) * 512 + lane * 8;
  unsigned int* slot_self =
      g_sync + mtile * 256 + ((jtile >> 3) << 5) + (jtile & 7);
  const unsigned int* slot_gather =
      g_sync + mtile * 256 + ((lane >> 3) << 5) + (lane & 7);
  unsigned int* go_base = g_sync + 1024 + mtile * 512;
  unsigned int* dcnt = g_sync + 3072 + mtile * 32;

  __syncthreads();

  for (int t = 0; t <= SS + 1; ++t) {
    // ---- acquire: h_t complete for this mtile ----
    if (t >= 1 && t <= SS) {
      if (jtile == 63) {
        // aggregator: gather all 64 slots (1 poller), then broadcast 16 copies
        if (wave == 0) {
          while (!__all((int)(__hip_atomic_load(slot_gather, __ATOMIC_RELAXED,
                                                __HIP_MEMORY_SCOPE_AGENT) >=
                              (unsigned)t)))
            __builtin_amdgcn_s_sleep(1);
          if (lane < 16)
            __hip_atomic_store(go_base + lane * 32, (unsigned)t,
                               __ATOMIC_RELAXED, __HIP_MEMORY_SCOPE_AGENT);
        }
      } else {
        if (wave == 0 && lane == 0) {
          const unsigned int* gp = go_base + (jtile & 15) * 32;
          while (__hip_atomic_load(gp, __ATOMIC_RELAXED,
                                   __HIP_MEMORY_SCOPE_AGENT) < (unsigned)t)
            __builtin_amdgcn_s_sleep(1);
        }
      }
      asm volatile("" ::: "memory");
      __syncthreads();
    }

    if (t < SS) {
      // ---- gates GEMM: wave computes 16 rows x 64 gate-cols, K=1088 ----
      float4v a0 = {0.f, 0.f, 0.f, 0.f}, a1 = {0.f, 0.f, 0.f, 0.f};
      float4v a2 = {0.f, 0.f, 0.f, 0.f}, a3 = {0.f, 0.f, 0.f, 0.f};
      const half_t* ap = habase + (size_t)t * BUFV;
      const half_t* bp = Wlds + lane * 8;
      #pragma unroll 8
      for (int kt = 0; kt < 32; ++kt) {
        const half8 av = *(const half8*)(ap + (size_t)kt * 512);
        a0 = MFMA16(av, *(const half8*)(bp + (size_t)(0 * NKT + kt) * 512), a0);
        a1 = MFMA16(av, *(const half8*)(bp + (size_t)(1 * NKT + kt) * 512), a1);
        a2 = MFMA16(av, *(const half8*)(bp + (size_t)(2 * NKT + kt) * 512), a2);
        a3 = MFMA16(av, *(const half8*)(bp + (size_t)(3 * NKT + kt) * 512), a3);
      }
      const half_t* xp = xA + (((size_t)t * 16 + mtA) * 2) * 512 + lane * 8;
      #pragma unroll
      for (int kt = 0; kt < 2; ++kt) {
        const half8 av = *(const half8*)(xp + (size_t)kt * 512);
        a0 = MFMA16(av, *(const half8*)(bp + (size_t)(0 * NKT + 32 + kt) * 512), a0);
        a1 = MFMA16(av, *(const half8*)(bp + (size_t)(1 * NKT + 32 + kt) * 512), a1);
        a2 = MFMA16(av, *(const half8*)(bp + (size_t)(2 * NKT + 32 + kt) * 512), a2);
        a3 = MFMA16(av, *(const half8*)(bp + (size_t)(3 * NKT + 32 + kt) * 512), a3);
      }

      // ---- intra-wave pre-activation exchange (no barrier) ----
      #pragma unroll
      for (int r = 0; r < 4; ++r) {
        const int rl = (kq * 4 + r) * PRE_STRIDE;
        pw[rl + rn] = a0[r];
        pw[rl + 16 + rn] = a1[r];
        pw[rl + 32 + rn] = a2[r];
        pw[rl + 48 + rn] = a3[r];
      }

      // ---- cell update (c in registers) ----
      const float4v pg0 = *(const float4v*)(pw + crow * PRE_STRIDE + hl);
      const float4v pg1 = *(const float4v*)(pw + crow * PRE_STRIDE + 16 + hl);
      const float4v pg2 = *(const float4v*)(pw + crow * PRE_STRIDE + 32 + hl);
      const float4v pg3 = *(const float4v*)(pw + crow * PRE_STRIDE + 48 + hl);
      half4 hnew;
      #pragma unroll
      for (int jj = 0; jj < 4; ++jj) {
        const float ig = pg0[jj] + bsum[0][jj];
        const float fg = pg1[jj] + bsum[1][jj];
        const float gg = pg2[jj] + bsum[2][jj];
        const float og = pg3[jj] + bsum[3][jj];
        const float is = 1.f / (1.f + __expf(-ig));
        const float fs = 1.f / (1.f + __expf(-fg));
        const float os = 1.f / (1.f + __expf(-og));
        const float gt = tanhf(gg);
        const float cn = fs * creg[jj] + is * gt;
        creg[jj] = cn;
        hnew[jj] = (half_t)(os * tanhf(cn));
      }
      astore8(g_hA + (size_t)(t + 1) * BUFV + hoff, hnew);

      // ---- release: h at LLC, then publish private slot (no RMW) ----
      __builtin_amdgcn_s_waitcnt(0);
      __syncthreads();
      if (tid == 0)
        __hip_atomic_store(slot_self, (unsigned)(t + 1), __ATOMIC_RELAXED,
                           __HIP_MEMORY_SCOPE_AGENT);
    }

    // ---- dense1 for h_{t-1}: 32 one-wave tasks per mtile (off critical path) ----
    if (t >= 1 && t <= SS && jtile < 32 && wave == 0) {
      const int rb = jtile >> 3, cb = jtile & 7;
      const int mt = mtile * 4 + rb;
      const half_t* ap = g_hA + (size_t)t * BUFV + ((size_t)mt * 32) * 512 + lane * 8;
      const half_t* bp = Wd_f + (size_t)cb * 32 * 512 + lane * 8;
      float4v acc = {0.f, 0.f, 0.f, 0.f};
      #pragma unroll 8
      for (int kt = 0; kt < 32; ++kt) {
        acc = MFMA16(*(const half8*)(ap + (size_t)kt * 512),
                     *(const half8*)(bp + (size_t)kt * 512), acc);
      }
      const int dcol = cb * 16 + rn;
      const float bv = bd[dcol];
      half_t* db = g_dbuf + (((size_t)(t - 1) * 16 + mt) * 16) * HEADD + dcol;
      #pragma unroll
      for (int r = 0; r < 4; ++r)
        astore2(db + (size_t)(kq * 4 + r) * HEADD, (half_t)fmaxf(acc[r] + bv, 0.f));
      __builtin_amdgcn_s_waitcnt(0);
      if (lane == 0)
        __hip_atomic_fetch_add(dcnt, 1u, __ATOMIC_RELAXED,
                               __HIP_MEMORY_SCOPE_AGENT);
    }

    // ---- dense2 for out step t-2: 16 one-wave tasks per mtile ----
    if (t >= 2 && jtile >= 32 && jtile < 48 && wave == 0) {
      if (lane == 0) {
        const unsigned tgt = 32u * (unsigned)(t - 1);
        while (__hip_atomic_load(dcnt, __ATOMIC_RELAXED,
                                 __HIP_MEMORY_SCOPE_AGENT) < tgt)
          __builtin_amdgcn_s_sleep(16);
      }
      asm volatile("" ::: "memory");
      const int task = jtile - 32;
      const int rb = task >> 2, cb2 = task & 3;
      const int mt = mtile * 4 + rb;
      const half_t* ap = g_dbuf + (((size_t)(t - 2) * 16 + mt) * 16) * HEADD;
      const half_t* bp = Wd2_f + (size_t)cb2 * 4 * 512 + lane * 8;
      float4v acc = {0.f, 0.f, 0.f, 0.f};
      #pragma unroll
      for (int kt = 0; kt < 4; ++kt) {
        const half8 af = *(const half8*)(ap + (size_t)rn * HEADD + kt * 32 + kq * 8);
        acc = MFMA16(af, *(const half8*)(bp + (size_t)kt * 512), acc);
      }
      const int ocol = cb2 * 16 + rn;
      const float bv = bd2[ocol];
      #pragma unroll
      for (int r = 0; r < 4; ++r) {
        const int row = m0 + rb * 16 + kq * 4 + r;
        out[(size_t)row * (SS * OUTD) + (size_t)(t - 2) * OUTD + ocol] = acc[r] + bv;
      }
    }
  }
}

extern "C" void kernel_launch(void* const* d_in, const int* in_sizes, int n_in,
                              void* d_out, int out_size, void* d_ws, size_t ws_size,
                              hipStream_t stream) {
  const float* x        = (const float*)d_in[0];
  const float* W_ih     = (const float*)d_in[1];
  const float* b_ih     = (const float*)d_in[2];
  const float* W_hh     = (const float*)d_in[3];
  const float* b_hh     = (const float*)d_in[4];
  const float* W_dense  = (const float*)d_in[5];
  const float* b_dense  = (const float*)d_in[6];
  const float* W_dense2 = (const float*)d_in[7];
  const float* b_dense2 = (const float*)d_in[8];
  float* out = (float*)d_out;

  char* p = (char*)d_ws;
  half_t* xA    = (half_t*)p; p += (size_t)SS * 16 * 1024 * 2;  // 16.8 MB
  half_t* Wd_f  = (half_t*)p; p += (size_t)8 * 32 * 512 * 2;    // 256 KB
  half_t* Wd2_f = (half_t*)p; p += (size_t)4 * 4 * 512 * 2;     // 16 KB

  init_state<<<256, 256, 0, stream>>>();
  pack_x<<<dim3(SS, 16), 256, 0, stream>>>(x, xA);
  frag_pack<<<HEADD / 16, 256, 0, stream>>>(W_dense, Wd_f, HH);
  frag_pack<<<OUTD / 16, 256, 0, stream>>>(W_dense2, Wd2_f, HEADD);

  hipFuncSetAttribute((const void*)lstm_persistent,
                      hipFuncAttributeMaxDynamicSharedMemorySize, SMEM_BYTES);
  void* args[] = {(void*)&W_hh, (void*)&W_ih, (void*)&b_ih, (void*)&b_hh,
                  (void*)&xA, (void*)&Wd_f, (void*)&b_dense,
                  (void*)&Wd2_f, (void*)&b_dense2, (void*)&out};
  hipLaunchCooperativeKernel((void*)lstm_persistent, dim3(256), dim3(256),
                             args, SMEM_BYTES, stream);
}